// Round 2
// baseline (410.494 us; speedup 1.0000x reference)
//
#include <hip/hip_runtime.h>

// MHA: B=8, N=1024, D=768, H=12, HD=64. FLOAT32 in/out, bf16 MFMA internally.
// Phase 1: QKV projection (per-head 64x64 GEMMs) f32 -> bf16 ws
// Phase 2: flash-style attention per (b,h) -> bf16 ws (in [B,N,D] layout)
// Phase 3: output projection [8192x768] @ Wo^T + bo -> f32 d_out

typedef __attribute__((ext_vector_type(8))) short short8;   // 8 x bf16 bits
typedef __attribute__((ext_vector_type(4))) float floatx4;  // MFMA acc

#define MFMA16(a, b, c) __builtin_amdgcn_mfma_f32_16x16x32_bf16((a), (b), (c), 0, 0, 0)

__device__ __forceinline__ unsigned short f2bf(float f) {
    union { float f; unsigned int i; } c;
    c.f = f;
    unsigned int i = c.i;
    return (unsigned short)((i + 0x7fffu + ((i >> 16) & 1u)) >> 16);  // RNE
}

// ---------------------------------------------------------------------------
// Phase 1: Q/K/V = xh @ W{q,k,v} + b{q,k,v}, per head. f32 inputs.
// grid (N/64, B*H), block 256 (4 waves, 16 rows each).
// ---------------------------------------------------------------------------
__global__ __launch_bounds__(256) void qkv_proj(
    const float* __restrict__ x,
    const float* __restrict__ Wq, const float* __restrict__ Wk,
    const float* __restrict__ Wv,
    const float* __restrict__ bq, const float* __restrict__ bk,
    const float* __restrict__ bv,
    unsigned short* __restrict__ Q, unsigned short* __restrict__ K,
    unsigned short* __restrict__ V)
{
    const int bh = blockIdx.y;
    const int b = bh / 12, h = bh % 12;
    const int wave = threadIdx.x >> 6, lane = threadIdx.x & 63;
    const int lrow = lane & 15, quad = lane >> 4;
    const int row0 = blockIdx.x * 64 + wave * 16;

    // A-frag: x[b, row0+lrow, h*64 + k], k = quad*8 + j (+32) — contiguous f32
    const float* xrow = x + ((size_t)(b * 1024 + row0 + lrow)) * 768 + h * 64;
    short8 a0, a1;
    #pragma unroll
    for (int j = 0; j < 8; ++j) {
        a0[j] = (short)f2bf(xrow[quad * 8 + j]);
        a1[j] = (short)f2bf(xrow[32 + quad * 8 + j]);
    }

    const float* Wm[3] = { Wq + h * 4096, Wk + h * 4096, Wv + h * 4096 };
    const float* bm[3] = { bq + h * 64, bk + h * 64, bv + h * 64 };
    unsigned short* Om[3] = { Q, K, V };

    const floatx4 zero = { 0.f, 0.f, 0.f, 0.f };

    for (int m = 0; m < 3; ++m) {
        const float* W = Wm[m];
        floatx4 acc[4];
        #pragma unroll
        for (int t = 0; t < 4; ++t) acc[t] = zero;

        #pragma unroll
        for (int t = 0; t < 4; ++t) {
            // B-frag: W[k][e], e = t*16+lrow, k = quad*8+j (+32): stride-64 loads
            short8 b0, b1;
            #pragma unroll
            for (int jj = 0; jj < 8; ++jj) {
                b0[jj] = (short)f2bf(W[(quad * 8 + jj) * 64 + t * 16 + lrow]);
                b1[jj] = (short)f2bf(W[(32 + quad * 8 + jj) * 64 + t * 16 + lrow]);
            }
            acc[t] = MFMA16(a0, b0, acc[t]);
            acc[t] = MFMA16(a1, b1, acc[t]);
        }

        unsigned short* O = Om[m] + ((size_t)bh * 1024 + row0) * 64;
        #pragma unroll
        for (int t = 0; t < 4; ++t) {
            float bias = bm[m][t * 16 + lrow];
            #pragma unroll
            for (int r = 0; r < 4; ++r) {
                // C/D: row = quad*4+r, col = t*16+lrow
                O[(quad * 4 + r) * 64 + t * 16 + lrow] = f2bf(acc[t][r] + bias);
            }
        }
    }
}

// ---------------------------------------------------------------------------
// Phase 2: flash attention per (b,h). grid (N/64, B*H), block 256.
// Each wave: 16 q-rows, online softmax, loop over 32-wide KV tiles.
// Q/K/V are bf16 in ws.
// ---------------------------------------------------------------------------
__global__ __launch_bounds__(256) void attn_kernel(
    const unsigned short* __restrict__ Q, const unsigned short* __restrict__ K,
    const unsigned short* __restrict__ V, unsigned short* __restrict__ AO)
{
    __shared__ __align__(16) unsigned short ldsP[4][16][32];  // per-wave P tile

    const int bh = blockIdx.y;
    const int b = bh / 12, h = bh % 12;
    const int wave = threadIdx.x >> 6, lane = threadIdx.x & 63;
    const int lrow = lane & 15, quad = lane >> 4;
    const int qrow0 = blockIdx.x * 64 + wave * 16;

    const unsigned short* Qb = Q + (size_t)bh * 1024 * 64;
    const unsigned short* Kb = K + (size_t)bh * 1024 * 64;
    const unsigned short* Vb = V + (size_t)bh * 1024 * 64;

    // Q A-frags, held in registers for the whole KV loop
    short8 aq0 = *(const short8*)(Qb + (size_t)(qrow0 + lrow) * 64 + quad * 8);
    short8 aq1 = *(const short8*)(Qb + (size_t)(qrow0 + lrow) * 64 + 32 + quad * 8);

    const floatx4 zero = { 0.f, 0.f, 0.f, 0.f };
    float mrow[4], ssum[4];
    floatx4 Oacc[4];
    #pragma unroll
    for (int r = 0; r < 4; ++r) { mrow[r] = -1e30f; ssum[r] = 0.f; }
    #pragma unroll
    for (int t = 0; t < 4; ++t) Oacc[t] = zero;

    const float scale = 0.03608439182435161f;  // 768^-0.5 (full-dim quirk)

    for (int jt = 0; jt < 32; ++jt) {
        const int j0 = jt * 32;
        // S = Q K^T: B-frag B[k=e][n=j] = K[j][e] -> contiguous row reads of K
        short8 b00 = *(const short8*)(Kb + (size_t)(j0 + lrow) * 64 + quad * 8);
        short8 b01 = *(const short8*)(Kb + (size_t)(j0 + lrow) * 64 + 32 + quad * 8);
        short8 b10 = *(const short8*)(Kb + (size_t)(j0 + 16 + lrow) * 64 + quad * 8);
        short8 b11 = *(const short8*)(Kb + (size_t)(j0 + 16 + lrow) * 64 + 32 + quad * 8);
        floatx4 S0 = zero, S1 = zero;
        S0 = MFMA16(aq0, b00, S0);
        S0 = MFMA16(aq1, b01, S0);
        S1 = MFMA16(aq0, b10, S1);
        S1 = MFMA16(aq1, b11, S1);

        float alpha[4];
        #pragma unroll
        for (int r = 0; r < 4; ++r) {
            float s0 = S0[r] * scale, s1 = S1[r] * scale;
            // row max across the 16 lanes of this quad group (cols)
            float v = fmaxf(s0, s1);
            v = fmaxf(v, __shfl_xor(v, 1));
            v = fmaxf(v, __shfl_xor(v, 2));
            v = fmaxf(v, __shfl_xor(v, 4));
            v = fmaxf(v, __shfl_xor(v, 8));
            float mn = fmaxf(mrow[r], v);
            alpha[r] = __expf(mrow[r] - mn);
            mrow[r] = mn;
            float p0 = __expf(s0 - mn), p1 = __expf(s1 - mn);
            S0[r] = p0; S1[r] = p1;
            float ts = p0 + p1;
            ts += __shfl_xor(ts, 1);
            ts += __shfl_xor(ts, 2);
            ts += __shfl_xor(ts, 4);
            ts += __shfl_xor(ts, 8);
            ssum[r] = ssum[r] * alpha[r] + ts;
        }
        #pragma unroll
        for (int t = 0; t < 4; ++t)
            #pragma unroll
            for (int r = 0; r < 4; ++r) Oacc[t][r] *= alpha[r];

        // P: C-layout -> LDS -> A-layout (bf16)
        #pragma unroll
        for (int r = 0; r < 4; ++r) {
            ldsP[wave][quad * 4 + r][lrow] = f2bf(S0[r]);
            ldsP[wave][quad * 4 + r][16 + lrow] = f2bf(S1[r]);
        }
        __syncthreads();
        short8 aP = *(const short8*)(&ldsP[wave][lrow][quad * 8]);

        // O += P V: B-frag B[k=j][n=e] = V[j0+k][e], stride-64 scalar loads
        #pragma unroll
        for (int t = 0; t < 4; ++t) {
            short8 bv_;
            #pragma unroll
            for (int jj = 0; jj < 8; ++jj)
                bv_[jj] = (short)Vb[(size_t)(j0 + quad * 8 + jj) * 64 + t * 16 + lrow];
            Oacc[t] = MFMA16(aP, bv_, Oacc[t]);
        }
        __syncthreads();
    }

    // epilogue: normalize, store to AO (bf16) in [B, N, D] layout (concat heads)
    #pragma unroll
    for (int t = 0; t < 4; ++t) {
        #pragma unroll
        for (int r = 0; r < 4; ++r) {
            float val = Oacc[t][r] / ssum[r];
            size_t idx = ((size_t)(b * 1024 + qrow0 + quad * 4 + r)) * 768
                       + h * 64 + t * 16 + lrow;
            AO[idx] = f2bf(val);
        }
    }
}

// ---------------------------------------------------------------------------
// Phase 3: Y = AO @ Wo^T + bo. A = AO [8192 x 768] bf16, Wo/bo f32, Y f32.
// grid (768/64, 8192/64), block 256.
// ---------------------------------------------------------------------------
__global__ __launch_bounds__(256) void out_proj(
    const unsigned short* __restrict__ AO, const float* __restrict__ Wo,
    const float* __restrict__ bo, float* __restrict__ Y)
{
    const int wave = threadIdx.x >> 6, lane = threadIdx.x & 63;
    const int lrow = lane & 15, quad = lane >> 4;
    const int row0 = blockIdx.y * 64 + wave * 16;
    const int c0 = blockIdx.x * 64;

    const floatx4 zero = { 0.f, 0.f, 0.f, 0.f };
    floatx4 acc[4];
    #pragma unroll
    for (int t = 0; t < 4; ++t) acc[t] = zero;

    for (int k0 = 0; k0 < 768; k0 += 32) {
        short8 a = *(const short8*)(AO + (size_t)(row0 + lrow) * 768 + k0 + quad * 8);
        #pragma unroll
        for (int t = 0; t < 4; ++t) {
            // B-frag: Wo[c][k] with c = c0+t*16+lrow -> contiguous f32 row reads
            const float* wrow = Wo + (size_t)(c0 + t * 16 + lrow) * 768 + k0 + quad * 8;
            short8 bfr;
            #pragma unroll
            for (int jj = 0; jj < 8; ++jj) bfr[jj] = (short)f2bf(wrow[jj]);
            acc[t] = MFMA16(a, bfr, acc[t]);
        }
    }
    #pragma unroll
    for (int t = 0; t < 4; ++t) {
        float bias = bo[c0 + t * 16 + lrow];
        #pragma unroll
        for (int r = 0; r < 4; ++r) {
            Y[(size_t)(row0 + quad * 4 + r) * 768 + c0 + t * 16 + lrow]
                = acc[t][r] + bias;
        }
    }
}

extern "C" void kernel_launch(void* const* d_in, const int* in_sizes, int n_in,
                              void* d_out, int out_size, void* d_ws, size_t ws_size,
                              hipStream_t stream)
{
    const float* x  = (const float*)d_in[0];
    const float* Wq = (const float*)d_in[1];
    const float* Wk = (const float*)d_in[2];
    const float* Wv = (const float*)d_in[3];
    const float* bq = (const float*)d_in[4];
    const float* bk = (const float*)d_in[5];
    const float* bv = (const float*)d_in[6];
    const float* Wo = (const float*)d_in[7];
    const float* bo = (const float*)d_in[8];

    // ws layout (bf16 elements): Q, K, V each B*H*N*HD = 6291456; AO = B*N*D
    unsigned short* Q  = (unsigned short*)d_ws;
    unsigned short* K  = Q + 6291456;
    unsigned short* V  = K + 6291456;
    unsigned short* AO = V + 6291456;
    float* Y = (float*)d_out;

    qkv_proj<<<dim3(16, 96), 256, 0, stream>>>(x, Wq, Wk, Wv, bq, bk, bv, Q, K, V);
    attn_kernel<<<dim3(16, 96), 256, 0, stream>>>(Q, K, V, AO);
    out_proj<<<dim3(12, 128), 256, 0, stream>>>(AO, Wo, bo, Y);
}